// Round 2
// baseline (5523.315 us; speedup 1.0000x reference)
//
#include <hip/hip_runtime.h>
#include <hip/hip_bf16.h>
#include <cstdint>
#include <cstddef>

#define HP 320   // padded hidden/N dim (300 -> 320)

typedef unsigned short ushortT;

__device__ __forceinline__ float b2f(ushortT u) {
    union { unsigned int i; float f; } v; v.i = ((unsigned int)u) << 16; return v.f;
}
__device__ __forceinline__ ushortT f2b(float f) {
    union { float f; unsigned int i; } v; v.f = f;
    unsigned int x = v.i;
    return (ushortT)((x + 0x7fffu + ((x >> 16) & 1u)) >> 16);
}

__device__ __forceinline__ void fma4(float4& c, float s, const float4 b) {
    c.x = fmaf(s, b.x, c.x);
    c.y = fmaf(s, b.y, c.y);
    c.z = fmaf(s, b.z, c.z);
    c.w = fmaf(s, b.w, c.w);
}
__device__ __forceinline__ float4 relu4(float4 v) {
    v.x = v.x > 0.f ? v.x : 0.f;
    v.y = v.y > 0.f ? v.y : 0.f;
    v.z = v.z > 0.f ? v.z : 0.f;
    v.w = v.w > 0.f ? v.w : 0.f;
    return v;
}
__device__ __forceinline__ float4 add4(float4 a, float4 b) {
    return make_float4(a.x + b.x, a.y + b.y, a.z + b.z, a.w + b.w);
}
__device__ __forceinline__ ushort4 pack4(float4 v) {
    ushort4 u;
    u.x = f2b(v.x); u.y = f2b(v.y); u.z = f2b(v.z); u.w = f2b(v.w);
    return u;
}

// ---------------------------------------------------------------- pad weights + bias
__global__ __launch_bounds__(256) void k_pad_weights(
    const float* __restrict__ Wi, const float* __restrict__ Wh,
    const float* __restrict__ Wo, const float* __restrict__ bo,
    float* __restrict__ Wip, float* __restrict__ Whp, float* __restrict__ Wop,
    float* __restrict__ bop) {
    int idx = blockIdx.x * 256 + threadIdx.x;
    if (idx < 160 * HP) {
        int k = idx / HP, n = idx - k * HP;
        Wip[idx] = (k < 147 && n < 300) ? Wi[k * 300 + n] : 0.f;
    }
    if (idx < HP * HP) {
        int k = idx / HP, n = idx - k * HP;
        Whp[idx] = (k < 300 && n < 300) ? Wh[k * 300 + n] : 0.f;
    }
    if (idx < 464 * HP) {
        int k = idx / HP, n = idx - k * HP;
        Wop[idx] = (k < 433 && n < 300) ? Wo[k * 300 + n] : 0.f;
    }
    if (idx < HP) bop[idx] = (idx < 300) ? bo[idx] : 0.f;
}

// ---------------------------------------------------------------- GEMM1: msg = relu(f_bonds @ W_i); optionally store inp
template <bool WRITE_INP>
__global__ __launch_bounds__(256) void k_gemm_bonds(
    const float* __restrict__ fb, const float* __restrict__ Wip,
    ushortT* __restrict__ inp, ushortT* __restrict__ msg, int nB) {
    __shared__ float As[16][68];
    __shared__ float Bs[16][HP];
    const int tid = threadIdx.x;
    const int row0 = blockIdx.x * 64;
    const int tx = tid & 15, ty = tid >> 4;
    const int kk = tid & 15, rb = tid >> 4;
    float4 acc[4][5];
#pragma unroll
    for (int i = 0; i < 4; i++)
#pragma unroll
        for (int j = 0; j < 5; j++) acc[i][j] = make_float4(0, 0, 0, 0);

    for (int kt = 0; kt < 160; kt += 16) {
#pragma unroll
        for (int i = 0; i < 4; i++) {
            int r = rb + 16 * i;
            int k = kt + kk;
            float v = 0.f;
            if (k < 147) v = fb[(size_t)(row0 + r) * 147 + k];
            As[kk][r] = v;
        }
#pragma unroll
        for (int j = 0; j < 20; j++) {
            int idx = tid + 256 * j;
            int k = idx / HP, n = idx - k * HP;
            Bs[k][n] = Wip[(size_t)(kt + k) * HP + n];
        }
        __syncthreads();
#pragma unroll
        for (int k = 0; k < 16; k++) {
            float4 a = *(const float4*)&As[k][ty * 4];
#pragma unroll
            for (int j = 0; j < 5; j++) {
                float4 b = *(const float4*)&Bs[k][tx * 4 + 64 * j];
                fma4(acc[0][j], a.x, b);
                fma4(acc[1][j], a.y, b);
                fma4(acc[2][j], a.z, b);
                fma4(acc[3][j], a.w, b);
            }
        }
        __syncthreads();
    }
#pragma unroll
    for (int i = 0; i < 4; i++) {
        size_t r = (size_t)row0 + ty * 4 + i;
#pragma unroll
        for (int j = 0; j < 5; j++) {
            int c = tx * 4 + 64 * j;
            size_t o = r * HP + c;
            float4 v = acc[i][j];
            if (WRITE_INP) *(ushort4*)&inp[o] = pack4(v);
            *(ushort4*)&msg[o] = pack4(relu4(v));
        }
    }
}

// ---------------------------------------------------------------- atom sum: amsg[a] = sum_j msg[a2b[a][j]]  (bf16 in/out, fp32 accum)
__global__ __launch_bounds__(256) void k_atom_sum(
    const ushortT* __restrict__ msg, const int* __restrict__ a2b,
    ushortT* __restrict__ amsg, int nA) {
    int t = blockIdx.x * 256 + threadIdx.x;
    int a = t / 40, q = t - a * 40;   // 40 chunks of 8 bf16 per 320-row
    if (a >= nA) return;
    float s[8];
#pragma unroll
    for (int e = 0; e < 8; e++) s[e] = 0.f;
#pragma unroll
    for (int j = 0; j < 6; j++) {
        int b = a2b[a * 6 + j];
        uint4 u = *(const uint4*)(msg + (size_t)b * HP + q * 8);
        s[0] += b2f(u.x & 0xffff); s[1] += b2f(u.x >> 16);
        s[2] += b2f(u.y & 0xffff); s[3] += b2f(u.y >> 16);
        s[4] += b2f(u.z & 0xffff); s[5] += b2f(u.z >> 16);
        s[6] += b2f(u.w & 0xffff); s[7] += b2f(u.w >> 16);
    }
    uint4 o;
    o.x = (unsigned)f2b(s[0]) | ((unsigned)f2b(s[1]) << 16);
    o.y = (unsigned)f2b(s[2]) | ((unsigned)f2b(s[3]) << 16);
    o.z = (unsigned)f2b(s[4]) | ((unsigned)f2b(s[5]) << 16);
    o.w = (unsigned)f2b(s[6]) | ((unsigned)f2b(s[7]) << 16);
    *(uint4*)(amsg + (size_t)a * HP + q * 8) = o;
}

// ---------------------------------------------------------------- GEMM2: msgout = relu(inp + (amsg[b2a]-msg[b2revb]) @ W_h)
// RECOMP: no inp buffer -> recompute f_bonds@W_i as a second K phase.
template <bool RECOMP>
__global__ __launch_bounds__(256) void k_gemm_msg(
    const ushortT* __restrict__ amsg, const ushortT* __restrict__ msgin,
    const int* __restrict__ b2a, const int* __restrict__ b2revb,
    const float* __restrict__ Whp, const float* __restrict__ Wip,
    const float* __restrict__ fb, const ushortT* __restrict__ inp,
    ushortT* __restrict__ msgout, int nB) {
    __shared__ float As[16][68];
    __shared__ float Bs[16][HP];
    __shared__ int offA[64], offR[64];
    const int tid = threadIdx.x;
    const int row0 = blockIdx.x * 64;
    const int tx = tid & 15, ty = tid >> 4;
    const int kk = tid & 15, rb = tid >> 4;
    if (tid < 64) {
        int b = row0 + tid;
        offA[tid] = b2a[b] * HP;
        offR[tid] = b2revb[b] * HP;
    }
    float4 acc[4][5];
#pragma unroll
    for (int i = 0; i < 4; i++)
#pragma unroll
        for (int j = 0; j < 5; j++) acc[i][j] = make_float4(0, 0, 0, 0);
    __syncthreads();

    // phase 1: gathered message diff @ W_h  (K = 320)
    for (int kt = 0; kt < HP; kt += 16) {
#pragma unroll
        for (int i = 0; i < 4; i++) {
            int r = rb + 16 * i;
            int k = kt + kk;
            As[kk][r] = b2f(amsg[(size_t)offA[r] + k]) - b2f(msgin[(size_t)offR[r] + k]);
        }
#pragma unroll
        for (int j = 0; j < 20; j++) {
            int idx = tid + 256 * j;
            int k = idx / HP, n = idx - k * HP;
            Bs[k][n] = Whp[(size_t)(kt + k) * HP + n];
        }
        __syncthreads();
#pragma unroll
        for (int k = 0; k < 16; k++) {
            float4 a = *(const float4*)&As[k][ty * 4];
#pragma unroll
            for (int j = 0; j < 5; j++) {
                float4 b = *(const float4*)&Bs[k][tx * 4 + 64 * j];
                fma4(acc[0][j], a.x, b);
                fma4(acc[1][j], a.y, b);
                fma4(acc[2][j], a.z, b);
                fma4(acc[3][j], a.w, b);
            }
        }
        __syncthreads();
    }

    // phase 2 (COMPACT only): += f_bonds @ W_i  (K = 160)
    if (RECOMP) {
        for (int kt = 0; kt < 160; kt += 16) {
#pragma unroll
            for (int i = 0; i < 4; i++) {
                int r = rb + 16 * i;
                int k = kt + kk;
                float v = 0.f;
                if (k < 147) v = fb[(size_t)(row0 + r) * 147 + k];
                As[kk][r] = v;
            }
#pragma unroll
            for (int j = 0; j < 20; j++) {
                int idx = tid + 256 * j;
                int k = idx / HP, n = idx - k * HP;
                Bs[k][n] = Wip[(size_t)(kt + k) * HP + n];
            }
            __syncthreads();
#pragma unroll
            for (int k = 0; k < 16; k++) {
                float4 a = *(const float4*)&As[k][ty * 4];
#pragma unroll
                for (int j = 0; j < 5; j++) {
                    float4 b = *(const float4*)&Bs[k][tx * 4 + 64 * j];
                    fma4(acc[0][j], a.x, b);
                    fma4(acc[1][j], a.y, b);
                    fma4(acc[2][j], a.z, b);
                    fma4(acc[3][j], a.w, b);
                }
            }
            __syncthreads();
        }
    }

#pragma unroll
    for (int i = 0; i < 4; i++) {
        size_t r = (size_t)row0 + ty * 4 + i;
#pragma unroll
        for (int j = 0; j < 5; j++) {
            int c = tx * 4 + 64 * j;
            size_t o = r * HP + c;
            float4 v = acc[i][j];
            if (!RECOMP) {
                ushort4 u = *(const ushort4*)&inp[o];
                v.x += b2f(u.x); v.y += b2f(u.y); v.z += b2f(u.z); v.w += b2f(u.w);
            }
            *(ushort4*)&msgout[o] = pack4(relu4(v));
        }
    }
}

// ---------------------------------------------------------------- GEMM3: ah = relu(concat(f_atoms, amsg) @ W_o + b_o)  -> fp32
__global__ __launch_bounds__(256) void k_gemm_atoms(
    const float* __restrict__ fa, const ushortT* __restrict__ amsg,
    const float* __restrict__ Wop, const float* __restrict__ bop,
    float* __restrict__ ah, int nA) {
    __shared__ float As[16][68];
    __shared__ float Bs[16][HP];
    const int tid = threadIdx.x;
    const int row0 = blockIdx.x * 64;
    const int tx = tid & 15, ty = tid >> 4;
    const int kk = tid & 15, rb = tid >> 4;
    float4 acc[4][5];
#pragma unroll
    for (int i = 0; i < 4; i++)
#pragma unroll
        for (int j = 0; j < 5; j++) acc[i][j] = make_float4(0, 0, 0, 0);

    for (int kt = 0; kt < 464; kt += 16) {
#pragma unroll
        for (int i = 0; i < 4; i++) {
            int r = rb + 16 * i;
            int k = kt + kk;
            int a = row0 + r;
            float v = 0.f;
            if (k < 133) v = fa[(size_t)a * 133 + k];
            else if (k < 453) v = b2f(amsg[(size_t)a * HP + (k - 133)]);
            As[kk][r] = v;
        }
#pragma unroll
        for (int j = 0; j < 20; j++) {
            int idx = tid + 256 * j;
            int k = idx / HP, n = idx - k * HP;
            Bs[k][n] = Wop[(size_t)(kt + k) * HP + n];
        }
        __syncthreads();
#pragma unroll
        for (int k = 0; k < 16; k++) {
            float4 a = *(const float4*)&As[k][ty * 4];
#pragma unroll
            for (int j = 0; j < 5; j++) {
                float4 b = *(const float4*)&Bs[k][tx * 4 + 64 * j];
                fma4(acc[0][j], a.x, b);
                fma4(acc[1][j], a.y, b);
                fma4(acc[2][j], a.z, b);
                fma4(acc[3][j], a.w, b);
            }
        }
        __syncthreads();
    }
#pragma unroll
    for (int i = 0; i < 4; i++) {
        size_t r = (size_t)row0 + ty * 4 + i;
#pragma unroll
        for (int j = 0; j < 5; j++) {
            int c = tx * 4 + 64 * j;
            float4 bias = *(const float4*)&bop[c];
            float4 v = relu4(add4(acc[i][j], bias));
            *(float4*)&ah[r * HP + c] = v;
        }
    }
}

// ---------------------------------------------------------------- mean pool
__global__ __launch_bounds__(256) void k_pool(
    const float* __restrict__ ah, float* __restrict__ out, int n_mols, int apm) {
    int t = blockIdx.x * 256 + threadIdx.x;
    if (t >= n_mols * 300) return;
    int m = t / 300, h = t - m * 300;
    const float* p = ah + (size_t)m * apm * HP + h;
    float s = 0.f;
    for (int u = 0; u < apm; u++) s += p[(size_t)u * HP];
    out[t] = s * (1.0f / (float)apm);
}

// ---------------------------------------------------------------- launch
extern "C" void kernel_launch(void* const* d_in, const int* in_sizes, int n_in,
                              void* d_out, int out_size, void* d_ws, size_t ws_size,
                              hipStream_t stream) {
    const float* fa     = (const float*)d_in[0];
    const float* fb     = (const float*)d_in[1];
    const int*   a2b    = (const int*)d_in[2];
    const int*   b2a    = (const int*)d_in[3];
    const int*   b2revb = (const int*)d_in[4];
    const float* Wi     = (const float*)d_in[5];
    const float* Wh     = (const float*)d_in[6];
    const float* Wo     = (const float*)d_in[7];
    const float* bo     = (const float*)d_in[8];

    const int nA     = in_sizes[0] / 133;   // 200000
    const int nB     = in_sizes[1] / 147;   // 400000
    const int n_mols = out_size / 300;      // 10000
    const int apm    = nA / n_mols;         // 20

    // ---- workspace layout (bytes) ----
    char* p = (char*)d_ws;
    float* Wip = (float*)p;  p += (size_t)160 * HP * 4;
    float* Whp = (float*)p;  p += (size_t)HP * HP * 4;
    float* Wop = (float*)p;  p += (size_t)464 * HP * 4;
    float* bop = (float*)p;  p += (size_t)HP * 4;
    p = (char*)(((uintptr_t)p + 255) & ~(uintptr_t)255);

    const size_t msgBytes  = (size_t)nB * HP * 2;   // one bf16 message buffer
    const size_t amsgBytes = (size_t)nA * HP * 2;
    const size_t headBytes = (size_t)(p - (char*)d_ws);
    const size_t needFull    = headBytes + 3 * msgBytes + amsgBytes;
    const size_t needCompact = headBytes + 2 * msgBytes + amsgBytes;
    const bool full = ws_size >= needFull;
    (void)needCompact;

    ushortT* msgA = (ushortT*)p;  p += msgBytes;
    ushortT* msgB = (ushortT*)p;  p += msgBytes;
    ushortT* amsg = (ushortT*)p;  p += amsgBytes;
    ushortT* inp  = full ? (ushortT*)p : nullptr;
    float*   ah   = (float*)msgA;   // reuse: msgA dead after last atom_sum (2*nA <= nB)
    float*   out  = (float*)d_out;

    k_pad_weights<<<(464 * HP + 255) / 256, 256, 0, stream>>>(Wi, Wh, Wo, bo, Wip, Whp, Wop, bop);

    if (full)
        k_gemm_bonds<true><<<nB / 64, 256, 0, stream>>>(fb, Wip, inp, msgA, nB);
    else
        k_gemm_bonds<false><<<nB / 64, 256, 0, stream>>>(fb, Wip, inp, msgA, nB);

    const int asum_grid = (int)(((size_t)nA * 40 + 255) / 256);

    // depth iteration 1: msgA -> msgB
    k_atom_sum<<<asum_grid, 256, 0, stream>>>(msgA, a2b, amsg, nA);
    if (full)
        k_gemm_msg<false><<<nB / 64, 256, 0, stream>>>(amsg, msgA, b2a, b2revb, Whp, Wip, fb, inp, msgB, nB);
    else
        k_gemm_msg<true><<<nB / 64, 256, 0, stream>>>(amsg, msgA, b2a, b2revb, Whp, Wip, fb, inp, msgB, nB);

    // depth iteration 2: msgB -> msgA
    k_atom_sum<<<asum_grid, 256, 0, stream>>>(msgB, a2b, amsg, nA);
    if (full)
        k_gemm_msg<false><<<nB / 64, 256, 0, stream>>>(amsg, msgB, b2a, b2revb, Whp, Wip, fb, inp, msgA, nB);
    else
        k_gemm_msg<true><<<nB / 64, 256, 0, stream>>>(amsg, msgB, b2a, b2revb, Whp, Wip, fb, inp, msgA, nB);

    // readout
    k_atom_sum<<<asum_grid, 256, 0, stream>>>(msgA, a2b, amsg, nA);
    k_gemm_atoms<<<nA / 64, 256, 0, stream>>>(fa, amsg, Wop, bop, ah, nA);
    k_pool<<<(n_mols * 300 + 255) / 256, 256, 0, stream>>>(ah, out, n_mols, apm);
}

// Round 3
// 2617.286 us; speedup vs baseline: 2.1103x; 2.1103x over previous
//
#include <hip/hip_runtime.h>
#include <hip/hip_bf16.h>
#include <cstdint>
#include <cstddef>

#define HP 320   // padded hidden/N dim (300 -> 320)

typedef unsigned short ushortT;
typedef __attribute__((ext_vector_type(8))) __bf16 bf16x8;
typedef __attribute__((ext_vector_type(4))) float f32x4;

__device__ __forceinline__ float b2f(unsigned u) {
    union { unsigned i; float f; } v; v.i = u << 16; return v.f;
}
__device__ __forceinline__ ushortT f2b(float f) {
    union { float f; unsigned i; } v; v.f = f;
    unsigned x = v.i;
    return (ushortT)((x + 0x7fffu + ((x >> 16) & 1u)) >> 16);
}
__device__ __forceinline__ unsigned subpk(unsigned a, unsigned r) {
    union { unsigned i; float f; } al, ah, rl, rh;
    al.i = a << 16; ah.i = a & 0xffff0000u;
    rl.i = r << 16; rh.i = r & 0xffff0000u;
    float lo = al.f - rl.f, hi = ah.f - rh.f;
    return (unsigned)f2b(lo) | ((unsigned)f2b(hi) << 16);
}

// ---------------------------------------------------------------- pack weights into MFMA B-fragment order
// packed[kt][nt(20)][kg(4)][col(16)][j(8)]  ==  W[kt*32+kg*8+j][nt*16+col]
__device__ __forceinline__ void pack_one(int idx, const float* __restrict__ W,
                                         int Ksrc, ushortT* __restrict__ dst) {
    int j = idx & 7, col = (idx >> 3) & 15, kg = (idx >> 7) & 3;
    int t = idx >> 9; int nt = t % 20, kt = t / 20;
    int k = kt * 32 + kg * 8 + j, n = nt * 16 + col;
    float v = (k < Ksrc && n < 300) ? W[k * 300 + n] : 0.f;
    dst[idx] = f2b(v);
}
// W_o remap: logical k<133 -> fa rows (src k), k in [160,460) -> amsg rows (src k-27), else 0
__device__ __forceinline__ void pack_wo(int idx, const float* __restrict__ W,
                                        ushortT* __restrict__ dst) {
    int j = idx & 7, col = (idx >> 3) & 15, kg = (idx >> 7) & 3;
    int t = idx >> 9; int nt = t % 20, kt = t / 20;
    int k = kt * 32 + kg * 8 + j, n = nt * 16 + col;
    int src = (k < 133) ? k : ((k >= 160 && k < 460) ? (k - 27) : -1);
    float v = (src >= 0 && n < 300) ? W[src * 300 + n] : 0.f;
    dst[idx] = f2b(v);
}

__global__ __launch_bounds__(256) void k_pack_weights(
    const float* __restrict__ Wi, const float* __restrict__ Wh,
    const float* __restrict__ Wo, const float* __restrict__ bo,
    ushortT* __restrict__ Wipk, ushortT* __restrict__ Whpk,
    ushortT* __restrict__ Wopk, float* __restrict__ bop) {
    int idx = blockIdx.x * 256 + threadIdx.x;
    if (idx < 51200)  pack_one(idx, Wi, 147, Wipk);   // K1 = 160 (5 ktiles)
    if (idx < 102400) pack_one(idx, Wh, 300, Whpk);   // K2 = 320 (10 ktiles)
    if (idx < 153600) pack_wo(idx, Wo, Wopk);         // K3 = 480 (15 ktiles)
    if (idx < HP) bop[idx] = (idx < 300) ? bo[idx] : 0.f;
}

// ---------------------------------------------------------------- unified MFMA GEMM
// MODE 0: A = f_bonds (fp32, K=160). AUX = write inp.     out: msgout (+inp)
// MODE 1: A = amsg[b2a]-msg[b2revb] (K=320). AUX = RECOMP (adds K=160 phase of f_bonds@Wi
//         instead of reading inp).                         out: msgout
// MODE 2: A = concat-relayout(fa | amsg) (K=480).          out: ahout fp32 (+bias, relu)
template <int MODE, bool AUX>
__global__ __launch_bounds__(256) void k_mfma(
    const float* __restrict__ fa, const float* __restrict__ fb,
    const ushortT* __restrict__ amsg, const ushortT* __restrict__ msgin,
    const int* __restrict__ b2a, const int* __restrict__ b2revb,
    const ushortT* __restrict__ Wpk, const ushortT* __restrict__ Wipk,
    const float* __restrict__ bop,
    const ushortT* __restrict__ inp_r, ushortT* __restrict__ inp_w,
    ushortT* __restrict__ msgout, float* __restrict__ ahout) {
    __shared__ ushortT A_lds[4 * 64 * 8];        // [kg][row][j]   4 KB
    __shared__ ushortT B_lds[20 * 4 * 16 * 8];   // [nt][kg][col][j] 20 KB
    __shared__ int offA[64], offR[64];
    const int tid = threadIdx.x, wave = tid >> 6, lane = tid & 63;
    const int row0 = blockIdx.x * 64;
    const int wm = wave >> 1, wn = wave & 1;
    if (MODE == 1 && tid < 64) {
        offA[tid] = b2a[row0 + tid] * HP;
        offR[tid] = b2revb[row0 + tid] * HP;
    }
    f32x4 acc[2][10];
#pragma unroll
    for (int i = 0; i < 2; i++)
#pragma unroll
        for (int n = 0; n < 10; n++) acc[i][n] = (f32x4){0.f, 0.f, 0.f, 0.f};
    const int NKT = (MODE == 0) ? 5 : (MODE == 1 ? 10 : 15);
    const int TOT = NKT + ((MODE == 1 && AUX) ? 5 : 0);
    __syncthreads();   // offA/offR visible

    for (int kts = 0; kts < TOT; kts++) {
        const bool ph2 = (MODE == 1 && AUX) && (kts >= 10);
        const int kt = ph2 ? (kts - 10) : kts;
        const ushortT* Bsrc = ph2 ? Wipk : Wpk;
        const int k0 = kt * 32 + wave * 8;

        // ---- A-stage: wave = kgroup, lane = row (16B per lane)
        union { ushortT u16[8]; uint4 v; } at;
        uint4 aw;
        if (MODE == 1 && !ph2) {
            uint4 ua = *(const uint4*)(amsg + (size_t)offA[lane] + k0);
            uint4 ur = *(const uint4*)(msgin + (size_t)offR[lane] + k0);
            aw.x = subpk(ua.x, ur.x); aw.y = subpk(ua.y, ur.y);
            aw.z = subpk(ua.z, ur.z); aw.w = subpk(ua.w, ur.w);
        } else if (MODE == 2 && kt >= 5) {
            aw = *(const uint4*)(amsg + (size_t)(row0 + lane) * HP + (k0 - 160));
        } else if (MODE == 2) {
#pragma unroll
            for (int j = 0; j < 8; j++) {
                int k = k0 + j;
                at.u16[j] = (k < 133) ? f2b(fa[(size_t)(row0 + lane) * 133 + k]) : (ushortT)0;
            }
            aw = at.v;
        } else {  // MODE 0 (or RECOMP phase 2): from f_bonds fp32
#pragma unroll
            for (int j = 0; j < 8; j++) {
                int k = k0 + j;
                at.u16[j] = (k < 147) ? f2b(fb[(size_t)(row0 + lane) * 147 + k]) : (ushortT)0;
            }
            aw = at.v;
        }

        // ---- B-stage: linear copy of packed tile (issue loads before barrier)
        uint4 breg[5];
        const uint4* bsrc = (const uint4*)(Bsrc + (size_t)kt * 10240);
#pragma unroll
        for (int i = 0; i < 5; i++) breg[i] = bsrc[tid + 256 * i];

        __syncthreads();   // previous iter's LDS reads done
        *(uint4*)&A_lds[wave * 512 + lane * 8] = aw;
#pragma unroll
        for (int i = 0; i < 5; i++) ((uint4*)B_lds)[tid + 256 * i] = breg[i];
        __syncthreads();

        // ---- compute: 2 m-tiles x 10 n-tiles per wave
        bf16x8 a0 = *(bf16x8*)&A_lds[(lane >> 4) * 512 + (wm * 32 + (lane & 15)) * 8];
        bf16x8 a1 = *(bf16x8*)&A_lds[(lane >> 4) * 512 + (wm * 32 + 16 + (lane & 15)) * 8];
#pragma unroll
        for (int n = 0; n < 10; n++) {
            bf16x8 b = *(bf16x8*)&B_lds[(wn * 10 + n) * 512 + (lane >> 4) * 128 + (lane & 15) * 8];
            acc[0][n] = __builtin_amdgcn_mfma_f32_16x16x32_bf16(a0, b, acc[0][n], 0, 0, 0);
            acc[1][n] = __builtin_amdgcn_mfma_f32_16x16x32_bf16(a1, b, acc[1][n], 0, 0, 0);
        }
    }

    // ---- epilogue: C frag layout col=lane&15, row=(lane>>4)*4+reg (m89/m91-verified)
#pragma unroll
    for (int i = 0; i < 2; i++) {
        int rl = wm * 32 + i * 16 + ((lane >> 4) << 2);
#pragma unroll
        for (int n = 0; n < 10; n++) {
            int col = wn * 160 + n * 16 + (lane & 15);
#pragma unroll
            for (int r = 0; r < 4; r++) {
                float v = acc[i][n][r];
                size_t o = (size_t)(row0 + rl + r) * HP + col;
                if (MODE == 0) {
                    if (AUX) inp_w[o] = f2b(v);
                    msgout[o] = f2b(fmaxf(v, 0.f));
                } else if (MODE == 1) {
                    if (!AUX) v += b2f((unsigned)inp_r[o]);
                    msgout[o] = f2b(fmaxf(v, 0.f));
                } else {
                    v += bop[col];
                    ahout[o] = fmaxf(v, 0.f);
                }
            }
        }
    }
}

// ---------------------------------------------------------------- atom sum (bf16 in/out, fp32 accum)
__global__ __launch_bounds__(256) void k_atom_sum(
    const ushortT* __restrict__ msg, const int* __restrict__ a2b,
    ushortT* __restrict__ amsg, int nA) {
    int t = blockIdx.x * 256 + threadIdx.x;
    int a = t / 40, q = t - a * 40;
    if (a >= nA) return;
    float s[8];
#pragma unroll
    for (int e = 0; e < 8; e++) s[e] = 0.f;
#pragma unroll
    for (int j = 0; j < 6; j++) {
        int b = a2b[a * 6 + j];
        uint4 u = *(const uint4*)(msg + (size_t)b * HP + q * 8);
        s[0] += b2f(u.x & 0xffff); s[1] += b2f(u.x >> 16);
        s[2] += b2f(u.y & 0xffff); s[3] += b2f(u.y >> 16);
        s[4] += b2f(u.z & 0xffff); s[5] += b2f(u.z >> 16);
        s[6] += b2f(u.w & 0xffff); s[7] += b2f(u.w >> 16);
    }
    uint4 o;
    o.x = (unsigned)f2b(s[0]) | ((unsigned)f2b(s[1]) << 16);
    o.y = (unsigned)f2b(s[2]) | ((unsigned)f2b(s[3]) << 16);
    o.z = (unsigned)f2b(s[4]) | ((unsigned)f2b(s[5]) << 16);
    o.w = (unsigned)f2b(s[6]) | ((unsigned)f2b(s[7]) << 16);
    *(uint4*)(amsg + (size_t)a * HP + q * 8) = o;
}

// ---------------------------------------------------------------- mean pool
__global__ __launch_bounds__(256) void k_pool(
    const float* __restrict__ ah, float* __restrict__ out, int n_mols, int apm) {
    int t = blockIdx.x * 256 + threadIdx.x;
    if (t >= n_mols * 300) return;
    int m = t / 300, h = t - m * 300;
    const float* p = ah + (size_t)m * apm * HP + h;
    float s = 0.f;
    for (int u = 0; u < apm; u++) s += p[(size_t)u * HP];
    out[t] = s * (1.0f / (float)apm);
}

// ---------------------------------------------------------------- launch
extern "C" void kernel_launch(void* const* d_in, const int* in_sizes, int n_in,
                              void* d_out, int out_size, void* d_ws, size_t ws_size,
                              hipStream_t stream) {
    const float* fa     = (const float*)d_in[0];
    const float* fb     = (const float*)d_in[1];
    const int*   a2b    = (const int*)d_in[2];
    const int*   b2a    = (const int*)d_in[3];
    const int*   b2revb = (const int*)d_in[4];
    const float* Wi     = (const float*)d_in[5];
    const float* Wh     = (const float*)d_in[6];
    const float* Wo     = (const float*)d_in[7];
    const float* bo     = (const float*)d_in[8];

    const int nA     = in_sizes[0] / 133;   // 200000
    const int nB     = in_sizes[1] / 147;   // 400000
    const int n_mols = out_size / 300;      // 10000
    const int apm    = nA / n_mols;         // 20

    char* p = (char*)d_ws;
    ushortT* Wipk = (ushortT*)p;  p += (size_t)51200 * 2;
    ushortT* Whpk = (ushortT*)p;  p += (size_t)102400 * 2;
    ushortT* Wopk = (ushortT*)p;  p += (size_t)153600 * 2;
    float*   bop  = (float*)p;    p += (size_t)HP * 4;
    p = (char*)(((uintptr_t)p + 255) & ~(uintptr_t)255);

    const size_t msgBytes  = (size_t)nB * HP * 2;
    const size_t amsgBytes = (size_t)nA * HP * 2;
    const size_t headBytes = (size_t)(p - (char*)d_ws);
    const bool full = ws_size >= headBytes + 3 * msgBytes + amsgBytes;

    ushortT* msgA = (ushortT*)p;  p += msgBytes;
    ushortT* msgB = (ushortT*)p;  p += msgBytes;
    ushortT* amsg = (ushortT*)p;  p += amsgBytes;
    ushortT* inp  = full ? (ushortT*)p : nullptr;
    float*   ah   = (float*)msgA;   // msgA dead after final atom_sum; nA*320*4 == msgBytes
    float*   out  = (float*)d_out;

    k_pack_weights<<<600, 256, 0, stream>>>(Wi, Wh, Wo, bo, Wipk, Whpk, Wopk, bop);

    // GEMM1: inp/msgA = f_bonds @ W_i
    if (full)
        k_mfma<0, true ><<<nB / 64, 256, 0, stream>>>(fa, fb, nullptr, nullptr, nullptr, nullptr,
                                                      Wipk, Wipk, bop, nullptr, inp, msgA, nullptr);
    else
        k_mfma<0, false><<<nB / 64, 256, 0, stream>>>(fa, fb, nullptr, nullptr, nullptr, nullptr,
                                                      Wipk, Wipk, bop, nullptr, nullptr, msgA, nullptr);

    const int asum_grid = (int)(((size_t)nA * 40 + 255) / 256);

    // depth 1: msgA -> msgB
    k_atom_sum<<<asum_grid, 256, 0, stream>>>(msgA, a2b, amsg, nA);
    if (full)
        k_mfma<1, false><<<nB / 64, 256, 0, stream>>>(fa, fb, amsg, msgA, b2a, b2revb,
                                                      Whpk, Wipk, bop, inp, nullptr, msgB, nullptr);
    else
        k_mfma<1, true ><<<nB / 64, 256, 0, stream>>>(fa, fb, amsg, msgA, b2a, b2revb,
                                                      Whpk, Wipk, bop, nullptr, nullptr, msgB, nullptr);

    // depth 2: msgB -> msgA
    k_atom_sum<<<asum_grid, 256, 0, stream>>>(msgB, a2b, amsg, nA);
    if (full)
        k_mfma<1, false><<<nB / 64, 256, 0, stream>>>(fa, fb, amsg, msgB, b2a, b2revb,
                                                      Whpk, Wipk, bop, inp, nullptr, msgA, nullptr);
    else
        k_mfma<1, true ><<<nB / 64, 256, 0, stream>>>(fa, fb, amsg, msgB, b2a, b2revb,
                                                      Whpk, Wipk, bop, nullptr, nullptr, msgA, nullptr);

    // readout
    k_atom_sum<<<asum_grid, 256, 0, stream>>>(msgA, a2b, amsg, nA);
    k_mfma<2, false><<<nA / 64, 256, 0, stream>>>(fa, fb, amsg, nullptr, nullptr, nullptr,
                                                  Wopk, Wipk, bop, nullptr, nullptr, nullptr, ah);
    k_pool<<<(n_mols * 300 + 255) / 256, 256, 0, stream>>>(ah, out, n_mols, apm);
}